// Round 5
// baseline (3662.931 us; speedup 1.0000x reference)
//
#include <hip/hip_runtime.h>

namespace {
constexpr int Tn = 4096;
constexpr int Kn = 64;
constexpr int BATCH = 128;
constexpr int START_TAG = 62;
constexpr int STOP_TAG = 63;
constexpr float NEGV = -10000.0f;
constexpr int CH = 64;          // backtrace chunk length
constexpr int NCH = Tn / CH;    // 64 chunks
constexpr int GL = 8;           // feats burst length (register-resident)
constexpr int NG = Tn / GL;     // 512 groups (8 per chunk)

__device__ __forceinline__ float rfl(float x) {
    return __uint_as_float(__builtin_amdgcn_readfirstlane(__float_as_uint(x)));
}
// zero-instruction scheduling fence (single-wave blocks need no s_barrier)
__device__ __forceinline__ void wbar() { __builtin_amdgcn_wave_barrier(); }

// One block (one wave) per batch: forward chain + Viterbi chain fused for ILP.
__global__ __launch_bounds__(64)
void crf_fused(const float* __restrict__ feats,   // [B,T,K]
               const int* __restrict__ tags,      // [B,T]
               const float* __restrict__ trans,   // [K,K]  trans[next,prev]
               float* __restrict__ out,           // [B] nll | [B] path_score | [B,T] path
               unsigned int* __restrict__ bp32)   // [B,T/4,K] packed backpointers
{
    const int lane = threadIdx.x;
    const int b = blockIdx.x;
    const size_t fb = (size_t)b * Tn * Kn;

    __shared__ float vbuf[2][Kn];   // forward exp(alpha - m)
    __shared__ float dbuf[2][Kn];   // viterbi delta
    __shared__ unsigned char snap[NCH * Kn];
    __shared__ unsigned char echain[NCH];

    // ---- gold path score: lane covers a contiguous 64-step chunk ----
    float gold = 0.0f;
    {
        const int t0 = lane * (Tn / 64);
        int prev = (lane == 0) ? START_TAG : tags[(size_t)b * Tn + t0 - 1];
        for (int k = 0; k < Tn / 64; ++k) {
            const int t = t0 + k;
            const int tg = tags[(size_t)b * Tn + t];
            gold += trans[tg * Kn + prev] + feats[fb + (size_t)t * Kn + tg];
            prev = tg;
        }
        if (lane == 63) gold += trans[STOP_TAG * Kn + prev];  // trans[STOP, tags[-1]]
    }
    #pragma unroll
    for (int off = 32; off; off >>= 1) gold += __shfl_down(gold, off);
    // gold total now on lane 0

    // ---- transition row for this lane: tr = trans[lane,:], E = exp(tr) ----
    float tr[Kn], E[Kn];
    #pragma unroll
    for (int q = 0; q < Kn / 4; ++q) {
        const float4 t4 = ((const float4*)(trans + lane * Kn))[q];
        tr[4*q+0] = t4.x; tr[4*q+1] = t4.y; tr[4*q+2] = t4.z; tr[4*q+3] = t4.w;
        E[4*q+0] = __expf(t4.x);
        E[4*q+1] = __expf(t4.y);
        E[4*q+2] = __expf(t4.z);
        E[4*q+3] = __expf(t4.w);
    }

    // ---- states ----
    float a;                                   // forward alpha (lane = tag)
    float d = (lane == START_TAG) ? 0.0f : NEGV;  // viterbi delta
    int h = lane;                              // composed backpointer table
    unsigned int bp4 = 0;                      // packed backpointer bytes
    const size_t dwb = (size_t)b * (Tn / 4);

    // fused per-step body: one wbar, interleaved q-loop so the scheduler can
    // fill one chain's stalls with the other chain's instructions.
    auto fused = [&](float f, int kk, int g) {
        const int par = kk & 1;
        const float m = rfl(a);                 // wave-uniform normalizer
        vbuf[par][lane] = __expf(a - m);
        dbuf[par][lane] = d;
        wbar();
        float s0 = 0.f, s1 = 0.f, s2 = 0.f, s3 = 0.f;
        float gv[16]; int gi[16];
        #pragma unroll
        for (int q = 0; q < 16; ++q) {
            const float4 vv = ((const float4*)vbuf[par])[q];
            const float4 dv = ((const float4*)dbuf[par])[q];
            // forward matvec (exp domain)
            s0 = fmaf(E[4*q+0], vv.x, s0);
            s1 = fmaf(E[4*q+1], vv.y, s1);
            s2 = fmaf(E[4*q+2], vv.z, s2);
            s3 = fmaf(E[4*q+3], vv.w, s3);
            // viterbi group argmax (strict '>' + lower-index-left = first-max)
            const float sx = dv.x + tr[4*q+0];
            const float sy = dv.y + tr[4*q+1];
            const float sz = dv.z + tr[4*q+2];
            const float sw = dv.w + tr[4*q+3];
            const bool c01 = sy > sx;
            const float v01 = c01 ? sy : sx; const int i01 = c01 ? (4*q+1) : (4*q+0);
            const bool c23 = sw > sz;
            const float v23 = c23 ? sw : sz; const int i23 = c23 ? (4*q+3) : (4*q+2);
            const bool cq = v23 > v01;
            gv[q] = cq ? v23 : v01; gi[q] = cq ? i23 : i01;
        }
        a = m + __logf((s0 + s1) + (s2 + s3)) + f;
        #pragma unroll
        for (int off = 8; off; off >>= 1) {
            #pragma unroll
            for (int q = 0; q < off; ++q) {
                const bool c = gv[q + off] > gv[q];
                gv[q] = c ? gv[q + off] : gv[q];
                gi[q] = c ? gi[q + off] : gi[q];
            }
        }
        const int bp = gi[0];
        d = gv[0] + f;                          // feat added after argmax (as ref)
        if ((kk & 3) == 0) bp4 = (unsigned int)bp;
        else bp4 |= (unsigned int)bp << (8 * (kk & 3));
        if ((kk & 3) == 3)
            bp32[(dwb + (size_t)(2 * g + (kk >> 2))) * Kn + lane] = bp4;
        h = __shfl(h, bp);                      // compose backpointer map
    };

    // viterbi-only step for t=0 (forward inits exactly from one-hot START)
    auto vit_only = [&](float f) {
        dbuf[0][lane] = d;
        wbar();
        float gv[16]; int gi[16];
        #pragma unroll
        for (int q = 0; q < 16; ++q) {
            const float4 dv = ((const float4*)dbuf[0])[q];
            const float sx = dv.x + tr[4*q+0];
            const float sy = dv.y + tr[4*q+1];
            const float sz = dv.z + tr[4*q+2];
            const float sw = dv.w + tr[4*q+3];
            const bool c01 = sy > sx;
            const float v01 = c01 ? sy : sx; const int i01 = c01 ? (4*q+1) : (4*q+0);
            const bool c23 = sw > sz;
            const float v23 = c23 ? sw : sz; const int i23 = c23 ? (4*q+3) : (4*q+2);
            const bool cq = v23 > v01;
            gv[q] = cq ? v23 : v01; gi[q] = cq ? i23 : i01;
        }
        #pragma unroll
        for (int off = 8; off; off >>= 1) {
            #pragma unroll
            for (int q = 0; q < off; ++q) {
                const bool c = gv[q + off] > gv[q];
                gv[q] = c ? gv[q + off] : gv[q];
                gi[q] = c ? gi[q + off] : gi[q];
            }
        }
        const int bp = gi[0];
        d = gv[0] + f;
        bp4 = (unsigned int)bp;                 // kk = 0
        h = __shfl(h, bp);
    };

    // ---- group 0 (t = 0..7), peeled for the t=0 special case ----
    float fc[GL], fn[GL];
    #pragma unroll
    for (int k = 0; k < GL; ++k) fc[k] = feats[fb + (size_t)k * Kn + lane];
    #pragma unroll
    for (int k = 0; k < GL; ++k) fn[k] = feats[fb + (size_t)(GL + k) * Kn + lane];
    a = tr[START_TAG] + fc[0];                  // alpha_0 = trans[lane,START] + feat0
    vit_only(fc[0]);
    #pragma unroll
    for (int k = 1; k < GL; ++k) fused(fc[k], k, 0);
    #pragma unroll
    for (int k = 0; k < GL; ++k) fc[k] = fn[k];

    // ---- groups 1..NG-1, double-buffered feats bursts ----
    for (int g = 1; g < NG; ++g) {
        if (g + 1 < NG) {
            const size_t base = fb + (size_t)(g + 1) * GL * Kn + lane;
            #pragma unroll
            for (int k = 0; k < GL; ++k) fn[k] = feats[base + (size_t)k * Kn];
        }
        #pragma unroll
        for (int k = 0; k < GL; ++k) fused(fc[k], k, g);
        #pragma unroll
        for (int k = 0; k < GL; ++k) fc[k] = fn[k];
        if ((g & 7) == 7) {                     // chunk boundary (64 steps)
            snap[(g >> 3) * Kn + lane] = (unsigned char)h;
            h = lane;
        }
    }

    const float tstop = trans[STOP_TAG * Kn + lane];

    // ---- forward tail: nll = logsumexp(alpha + trans[STOP,:]) - gold ----
    {
        const float x = a + tstop;
        float mx = x;
        #pragma unroll
        for (int off = 32; off; off >>= 1) mx = fmaxf(mx, __shfl_xor(mx, off));
        float se = __expf(x - mx);
        #pragma unroll
        for (int off = 32; off; off >>= 1) se += __shfl_xor(se, off);
        if (lane == 0) out[b] = (mx + __logf(se)) - gold;
    }

    // ---- viterbi tail: terminal argmax (first index on ties) ----
    const float term = d + tstop;
    float bv = term;
    int bi = lane;
    #pragma unroll
    for (int off = 32; off; off >>= 1) {
        const float ov = __shfl_xor(bv, off);
        const int oi = __shfl_xor(bi, off);
        if (ov > bv || (ov == bv && oi < bi)) { bv = ov; bi = oi; }
    }
    if (lane == 0) out[BATCH + b] = bv;         // path_score
    wbar();
    // ---- chunk-boundary tags via composed tables ----
    if (lane == 0) {
        int e = bi;
        for (int c = NCH - 1; c >= 0; --c) {
            echain[c] = (unsigned char)e;
            e = snap[c * Kn + e];
        }
    }
    wbar();
    // ---- within-chunk reconstruction: lane = chunk ----
    {
        int tag = echain[lane];
        float* po = out + 2 * BATCH + (size_t)b * Tn;
        for (int k = CH - 1; k >= 0; --k) {
            const int t = lane * CH + k;
            po[t] = (float)tag;
            tag = (int)((bp32[(dwb + (size_t)(t >> 2)) * Kn + tag] >> (8 * (t & 3))) & 63u);
        }
    }
}
} // namespace

extern "C" void kernel_launch(void* const* d_in, const int* in_sizes, int n_in,
                              void* d_out, int out_size, void* d_ws, size_t ws_size,
                              hipStream_t stream)
{
    const float* feats = (const float*)d_in[0];
    const int* tags   = (const int*)d_in[1];
    const float* trans = (const float*)d_in[2];
    float* out = (float*)d_out;
    unsigned int* bp = (unsigned int*)d_ws;  // needs 128*4096*64 B = 32 MB
    hipLaunchKernelGGL(crf_fused, dim3(BATCH), dim3(64), 0, stream,
                       feats, tags, trans, out, bp);
}

// Round 6
// 2655.542 us; speedup vs baseline: 1.3794x; 1.3794x over previous
//
#include <hip/hip_runtime.h>

namespace {
constexpr int Tn = 4096;
constexpr int Kn = 64;
constexpr int BATCH = 128;
constexpr int START_TAG = 62;
constexpr int STOP_TAG = 63;
constexpr float NEGV = -10000.0f;
constexpr int CH = 64;          // backtrace chunk length
constexpr int NCH = Tn / CH;    // 64 chunks
constexpr int GL = 8;           // feats burst length (register-resident)
constexpr int NG = Tn / GL;     // 512 groups
constexpr int TRP = 68;         // padded tr_lds row stride (floats); 68*4B, 16B-aligned

__device__ __forceinline__ float rfl(float x) {
    return __uint_as_float(__builtin_amdgcn_readfirstlane(__float_as_uint(x)));
}
// zero-instruction scheduling fence (single-wave blocks need no s_barrier)
__device__ __forceinline__ void wbar() { __builtin_amdgcn_wave_barrier(); }

__global__ __launch_bounds__(64)
void crf_kernel(const float* __restrict__ feats,   // [B,T,K]
                const int* __restrict__ tags,      // [B,T]
                const float* __restrict__ trans,   // [K,K]  trans[next,prev]
                float* __restrict__ out,           // [B] nll | [B] path_score | [B,T] path
                unsigned int* __restrict__ bp32)   // [B,T/4,K] packed backpointers
{
    const int lane = threadIdx.x;
    const int b = blockIdx.x & (BATCH - 1);
    const size_t fb = (size_t)b * Tn * Kn;

    __shared__ float sbuf[2][Kn];          // fwd: v vector | vit: delta vector
    __shared__ float tr_lds[Kn * TRP];     // vit: padded copy of trans rows
    __shared__ unsigned char snap[NCH * Kn];
    __shared__ unsigned char echain[NCH];

    if (blockIdx.x < BATCH) {
        // ================= forward partition + gold score -> nll =================
        float gold = 0.0f;
        {
            const int t0 = lane * (Tn / 64);
            int prev = (lane == 0) ? START_TAG : tags[(size_t)b * Tn + t0 - 1];
            for (int k = 0; k < Tn / 64; ++k) {
                const int t = t0 + k;
                const int tg = tags[(size_t)b * Tn + t];
                gold += trans[tg * Kn + prev] + feats[fb + (size_t)t * Kn + tg];
                prev = tg;
            }
            if (lane == 63) gold += trans[STOP_TAG * Kn + prev];  // trans[STOP, tags[-1]]
        }
        #pragma unroll
        for (int off = 32; off; off >>= 1) gold += __shfl_down(gold, off);
        // gold total on lane 0

        // ---- E row (exp of transitions): lane j owns trans[j,:] ----
        float E[Kn];
        #pragma unroll
        for (int q = 0; q < Kn / 4; ++q) {
            const float4 t4 = ((const float4*)(trans + lane * Kn))[q];
            E[4*q+0] = __expf(t4.x);
            E[4*q+1] = __expf(t4.y);
            E[4*q+2] = __expf(t4.z);
            E[4*q+3] = __expf(t4.w);
        }

        // ---- exp-domain normalized state: v[j] = exp(alpha[j] - m), O = m ----
        float v, O;

        // step: w[j] = (sum_i E[j,i] v[i]) * F[j];  v' = w / w0;  O += log w0.
        // exp/log are OFF the critical chain (F precomputed; log feeds only O).
        auto fwd_step = [&](float F, int par) {
            float* vb = sbuf[par];
            vb[lane] = v;
            wbar();
            float s0 = 0.f, s1 = 0.f, s2 = 0.f, s3 = 0.f;
            float s4 = 0.f, s5 = 0.f, s6 = 0.f, s7 = 0.f;
            #pragma unroll
            for (int q = 0; q < 16; q += 2) {
                const float4 v0 = ((const float4*)vb)[q];
                const float4 v1 = ((const float4*)vb)[q + 1];
                s0 = fmaf(E[4*q+0], v0.x, s0);
                s1 = fmaf(E[4*q+1], v0.y, s1);
                s2 = fmaf(E[4*q+2], v0.z, s2);
                s3 = fmaf(E[4*q+3], v0.w, s3);
                s4 = fmaf(E[4*q+4], v1.x, s4);
                s5 = fmaf(E[4*q+5], v1.y, s5);
                s6 = fmaf(E[4*q+6], v1.z, s6);
                s7 = fmaf(E[4*q+7], v1.w, s7);
            }
            const float w = (((s0 + s4) + (s1 + s5)) + ((s2 + s6) + (s3 + s7))) * F;
            const float w0 = rfl(w);
            O += __logf(w0);                         // off-chain accumulation
            v = w * __builtin_amdgcn_rcpf(w0);       // v[0] == 1 exactly-ish
        };

        // ---- bursts with F = exp(feat) precomputed off-chain ----
        float fc[GL], fn[GL], Fc[GL];
        #pragma unroll
        for (int k = 0; k < GL; ++k) fc[k] = feats[fb + (size_t)k * Kn + lane];
        #pragma unroll
        for (int k = 0; k < GL; ++k) fn[k] = feats[fb + (size_t)(GL + k) * Kn + lane];
        // step 0 exact (one-hot init at START)
        {
            const float a0 = trans[lane * Kn + START_TAG] + fc[0];
            const float m0 = rfl(a0);
            v = __expf(a0 - m0);
            O = m0;
        }
        #pragma unroll
        for (int k = 1; k < GL; ++k) Fc[k] = __expf(fc[k]);
        #pragma unroll
        for (int k = 1; k < GL; ++k) fwd_step(Fc[k], k & 1);
        #pragma unroll
        for (int k = 0; k < GL; ++k) fc[k] = fn[k];

        for (int g = 1; g < NG; ++g) {
            if (g + 1 < NG) {
                const size_t base = fb + (size_t)(g + 1) * GL * Kn + lane;
                #pragma unroll
                for (int k = 0; k < GL; ++k) fn[k] = feats[base + (size_t)k * Kn];
            }
            #pragma unroll
            for (int k = 0; k < GL; ++k) Fc[k] = __expf(fc[k]);
            #pragma unroll
            for (int k = 0; k < GL; ++k) fwd_step(Fc[k], k & 1);
            #pragma unroll
            for (int k = 0; k < GL; ++k) fc[k] = fn[k];
        }

        // ---- reconstruct alpha, then nll = logsumexp(alpha + trans[STOP,:]) - gold
        const float a = O + __logf(v);               // v==0 -> -inf, fine
        const float x = a + trans[STOP_TAG * Kn + lane];
        float mx = x;
        #pragma unroll
        for (int off = 32; off; off >>= 1) mx = fmaxf(mx, __shfl_xor(mx, off));
        float se = __expf(x - mx);
        #pragma unroll
        for (int off = 32; off; off >>= 1) se += __shfl_xor(se, off);
        if (lane == 0) out[b] = (mx + __logf(se)) - gold;
    } else {
        // ================= Viterbi decode =================
        float tr[Kn];
        #pragma unroll
        for (int q = 0; q < Kn / 4; ++q) {
            const float4 t4 = ((const float4*)(trans + lane * Kn))[q];
            tr[4*q+0] = t4.x; tr[4*q+1] = t4.y; tr[4*q+2] = t4.z; tr[4*q+3] = t4.w;
            ((float4*)(tr_lds + lane * TRP))[q] = t4;  // padded LDS copy for bp recovery
        }
        float d = (lane == START_TAG) ? 0.0f : NEGV;
        int h = lane;           // running composed backpointer table
        unsigned int bp4 = 0;   // packed backpointer bytes
        const size_t dwb = (size_t)b * (Tn / 4);

        // Slim step: value-only max on the critical chain (max3-friendly trees),
        // backpointer recovered OFF-chain by equality scan + LDS recompute.
        auto vit_step = [&](float f, int par, int kk, int g) {
            float* db = sbuf[par];
            db[lane] = d;
            wbar();
            float gmax[16];
            #pragma unroll
            for (int q = 0; q < 16; ++q) {
                const float4 dv = ((const float4*)db)[q];
                const float sx = dv.x + tr[4*q+0];
                const float sy = dv.y + tr[4*q+1];
                const float sz = dv.z + tr[4*q+2];
                const float sw = dv.w + tr[4*q+3];
                gmax[q] = fmaxf(fmaxf(fmaxf(sx, sy), sz), sw);  // -> v_max3 + v_max
            }
            // global max, shallow tree (compiler forms v_max3)
            float t0 = fmaxf(fmaxf(gmax[0],  gmax[1]),  gmax[2]);
            float t1 = fmaxf(fmaxf(gmax[3],  gmax[4]),  gmax[5]);
            float t2 = fmaxf(fmaxf(gmax[6],  gmax[7]),  gmax[8]);
            float t3 = fmaxf(fmaxf(gmax[9],  gmax[10]), gmax[11]);
            float t4 = fmaxf(fmaxf(gmax[12], gmax[13]), gmax[14]);
            const float best = fmaxf(fmaxf(fmaxf(t0, t1), fmaxf(t2, t3)),
                                     fmaxf(t4, gmax[15]));
            d = best + f;                          // critical chain ends here
            // ---- off-chain backpointer recovery (first-max semantics) ----
            int bg = 15;
            #pragma unroll
            for (int q = 14; q >= 0; --q) bg = (gmax[q] == best) ? q : bg;
            const int base = 4 * bg;
            const float4 dd = *(const float4*)(db + base);             // broadcast-ish
            const float4 tt = *(const float4*)(tr_lds + lane * TRP + base);
            const float r0 = dd.x + tt.x;
            const float r1 = dd.y + tt.y;
            const float r2 = dd.z + tt.z;
            const int bp = base + (r0 == best ? 0 : (r1 == best ? 1 : (r2 == best ? 2 : 3)));
            if ((kk & 3) == 0) bp4 = (unsigned int)bp;
            else bp4 |= (unsigned int)bp << (8 * (kk & 3));
            if ((kk & 3) == 3)
                bp32[(dwb + (size_t)(2 * g + (kk >> 2))) * Kn + lane] = bp4;
            h = __shfl(h, bp);                     // compose backpointer map
        };

        // ---- 64 chunks x (8 groups of 8 steps), double-buffered feats bursts ----
        float fc[GL], fn[GL];
        #pragma unroll
        for (int k = 0; k < GL; ++k) fc[k] = feats[fb + (size_t)k * Kn + lane];
        for (int c = 0; c < NCH; ++c) {
            for (int gg = 0; gg < CH / GL; ++gg) {
                const int g = (CH / GL) * c + gg;
                if (g + 1 < NG) {
                    const size_t base = fb + (size_t)(g + 1) * GL * Kn + lane;
                    #pragma unroll
                    for (int k = 0; k < GL; ++k) fn[k] = feats[base + (size_t)k * Kn];
                }
                #pragma unroll
                for (int k = 0; k < GL; ++k) vit_step(fc[k], k & 1, k, g);
                #pragma unroll
                for (int k = 0; k < GL; ++k) fc[k] = fn[k];
            }
            snap[c * Kn + lane] = (unsigned char)h;  // chunk-composed table
            h = lane;
        }

        // ---- terminal argmax (first index on ties) ----
        const float term = d + trans[STOP_TAG * Kn + lane];
        float bv = term;
        int bi = lane;
        #pragma unroll
        for (int off = 32; off; off >>= 1) {
            const float ov = __shfl_xor(bv, off);
            const int oi = __shfl_xor(bi, off);
            if (ov > bv || (ov == bv && oi < bi)) { bv = ov; bi = oi; }
        }
        if (lane == 0) out[BATCH + b] = bv;   // path_score
        wbar();
        // ---- chunk-boundary tags via composed tables ----
        if (lane == 0) {
            int e = bi;
            for (int c = NCH - 1; c >= 0; --c) {
                echain[c] = (unsigned char)e;
                e = snap[c * Kn + e];
            }
        }
        wbar();
        // ---- within-chunk reconstruction: lane = chunk ----
        {
            int tag = echain[lane];
            float* po = out + 2 * BATCH + (size_t)b * Tn;
            for (int k = CH - 1; k >= 0; --k) {
                const int t = lane * CH + k;
                po[t] = (float)tag;
                tag = (int)((bp32[(dwb + (size_t)(t >> 2)) * Kn + tag] >> (8 * (t & 3))) & 63u);
            }
        }
    }
}
} // namespace

extern "C" void kernel_launch(void* const* d_in, const int* in_sizes, int n_in,
                              void* d_out, int out_size, void* d_ws, size_t ws_size,
                              hipStream_t stream)
{
    const float* feats = (const float*)d_in[0];
    const int* tags   = (const int*)d_in[1];
    const float* trans = (const float*)d_in[2];
    float* out = (float*)d_out;
    unsigned int* bp = (unsigned int*)d_ws;  // needs 128*4096*64 B = 32 MB
    hipLaunchKernelGGL(crf_kernel, dim3(2 * BATCH), dim3(64), 0, stream,
                       feats, tags, trans, out, bp);
}

// Round 7
// 1740.062 us; speedup vs baseline: 2.1051x; 1.5261x over previous
//
#include <hip/hip_runtime.h>

namespace {
constexpr int Tn = 4096;
constexpr int Kn = 64;
constexpr int BATCH = 128;
constexpr int START_TAG = 62;
constexpr int STOP_TAG = 63;
constexpr float NEGV = -10000.0f;
constexpr int CH = 64;          // backtrace chunk length
constexpr int NCH = Tn / CH;    // 64 chunks
constexpr int GL = 8;           // feats burst length
constexpr int NG = Tn / GL;     // 512 groups
constexpr int WV = 4;           // waves per block
constexpr int SL = Kn / WV;     // 16 prev-states per wave
constexpr int KP = 66;          // padded partial stride

__device__ __forceinline__ float rfl(float x) {
    return __uint_as_float(__builtin_amdgcn_readfirstlane(__float_as_uint(x)));
}
// LDS-only barrier: waits lgkmcnt but NOT vmcnt, so global bursts stay in flight.
__device__ __forceinline__ void bar() {
    __asm__ volatile("s_waitcnt lgkmcnt(0)\n\ts_barrier" ::: "memory");
}
__device__ __forceinline__ void vmdrain() {
    __asm__ volatile("s_waitcnt vmcnt(0)" ::: "memory");
}
// monotone float->u32 map (preserves fp32 ordering exactly)
__device__ __forceinline__ unsigned int fkey(float x) {
    unsigned int b = __float_as_uint(x);
    return (b & 0x80000000u) ? ~b : (b | 0x80000000u);
}
__device__ __forceinline__ float unkey(unsigned int hb) {
    return __uint_as_float((hb & 0x80000000u) ? (hb ^ 0x80000000u) : ~hb);
}

__global__ __launch_bounds__(256)
void crf_kernel(const float* __restrict__ feats,   // [B,T,K]
                const int* __restrict__ tags,      // [B,T]
                const float* __restrict__ trans,   // [K,K]  trans[next,prev]
                float* __restrict__ out,           // [B] nll | [B] path_score | [B,T] path
                unsigned int* __restrict__ bp32)   // [B,T/4,K] packed backpointers
{
    const int tid = threadIdx.x;
    const int lane = tid & 63;
    const int wid = tid >> 6;
    const int b = blockIdx.x & (BATCH - 1);
    const size_t fb = (size_t)b * Tn * Kn;

    __shared__ float sb[2][Kn];                   // fwd: v | vit: d
    __shared__ unsigned long long kp[2][WV * KP]; // vit partial keys
    __shared__ float wp[2][WV * KP];              // fwd partial sums
    __shared__ unsigned char snap[NCH * Kn];
    __shared__ unsigned char echain[NCH];

    if (blockIdx.x < BATCH) {
        // ================= forward log-partition + gold -> nll =================
        float gold = 0.0f;
        if (wid == 0) {
            const int t0 = lane * (Tn / 64);
            int prev = (lane == 0) ? START_TAG : tags[(size_t)b * Tn + t0 - 1];
            for (int k = 0; k < Tn / 64; ++k) {
                const int t = t0 + k;
                const int tg = tags[(size_t)b * Tn + t];
                gold += trans[tg * Kn + prev] + feats[fb + (size_t)t * Kn + tg];
                prev = tg;
            }
            if (lane == 63) gold += trans[STOP_TAG * Kn + prev];
            #pragma unroll
            for (int off = 32; off; off >>= 1) gold += __shfl_down(gold, off);
        }
        // slice of exp(trans): ES[s] = exp(trans[lane, wid*16+s])
        float ES[SL];
        #pragma unroll
        for (int q = 0; q < SL / 4; ++q) {
            const float4 t4 = ((const float4*)(trans + lane * Kn + wid * SL))[q];
            ES[4*q+0] = __expf(t4.x); ES[4*q+1] = __expf(t4.y);
            ES[4*q+2] = __expf(t4.z); ES[4*q+3] = __expf(t4.w);
        }
        // exp-domain one-hot init: v=1 at START else 0; O=0. Generic step at t=0
        // then reproduces ref's step-0 exactly in fp32 (others underflow to 0).
        if (wid == 0) sb[0][lane] = (lane == START_TAG) ? 1.0f : 0.0f;
        float O = 0.0f, v = 0.0f;

        float fc[GL], fn[GL], Fc[GL];
        #pragma unroll
        for (int k = 0; k < GL; ++k) fc[k] = feats[fb + (size_t)k * Kn + lane];
        bar();
        for (int g = 0; g < NG; ++g) {
            if (g + 1 < NG) {
                const size_t base = fb + (size_t)(g + 1) * GL * Kn + lane;
                #pragma unroll
                for (int k = 0; k < GL; ++k) fn[k] = feats[base + (size_t)k * Kn];
            }
            #pragma unroll
            for (int k = 0; k < GL; ++k) Fc[k] = __expf(fc[k]);
            #pragma unroll
            for (int k = 0; k < GL; ++k) {
                const int t = g * GL + k;
                const int p = t & 1;
                // ---- phase A: partial dot over this wave's 16 prev states ----
                const float4* vp = (const float4*)&sb[p][wid * SL];
                const float4 v0 = vp[0], v1 = vp[1], v2 = vp[2], v3 = vp[3];
                float s0 = 0.f, s1 = 0.f, s2 = 0.f, s3 = 0.f;
                s0 = fmaf(ES[0],  v0.x, s0); s1 = fmaf(ES[1],  v0.y, s1);
                s2 = fmaf(ES[2],  v0.z, s2); s3 = fmaf(ES[3],  v0.w, s3);
                s0 = fmaf(ES[4],  v1.x, s0); s1 = fmaf(ES[5],  v1.y, s1);
                s2 = fmaf(ES[6],  v1.z, s2); s3 = fmaf(ES[7],  v1.w, s3);
                s0 = fmaf(ES[8],  v2.x, s0); s1 = fmaf(ES[9],  v2.y, s1);
                s2 = fmaf(ES[10], v2.z, s2); s3 = fmaf(ES[11], v2.w, s3);
                s0 = fmaf(ES[12], v3.x, s0); s1 = fmaf(ES[13], v3.y, s1);
                s2 = fmaf(ES[14], v3.z, s2); s3 = fmaf(ES[15], v3.w, s3);
                wp[p][wid * KP + lane] = (s0 + s1) + (s2 + s3);
                bar();
                // ---- phase B: combine 4 partials (fixed order), renormalize ----
                const float w0r = wp[p][0 * KP + lane];
                const float w1r = wp[p][1 * KP + lane];
                const float w2r = wp[p][2 * KP + lane];
                const float w3r = wp[p][3 * KP + lane];
                const float w = ((w0r + w1r) + (w2r + w3r)) * Fc[k];
                const float wz = rfl(w);               // lane-0 value > 0
                O += __logf(wz);                       // off-chain log accumulation
                v = w * __builtin_amdgcn_rcpf(wz);
                if (wid == 0) sb[p ^ 1][lane] = v;
                bar();
            }
            #pragma unroll
            for (int k = 0; k < GL; ++k) fc[k] = fn[k];
        }
        // ---- nll = logsumexp(alpha + trans[STOP,:]) - gold (wave 0 writes) ----
        if (wid == 0) {
            const float a = O + __logf(v);             // v==0 -> -inf, fine
            const float x = a + trans[STOP_TAG * Kn + lane];
            float mx = x;
            #pragma unroll
            for (int off = 32; off; off >>= 1) mx = fmaxf(mx, __shfl_xor(mx, off));
            float se = __expf(x - mx);
            #pragma unroll
            for (int off = 32; off; off >>= 1) se += __shfl_xor(se, off);
            if (lane == 0) out[b] = (mx + __logf(se)) - gold;
        }
    } else {
        // ================= Viterbi decode (exact fp32) =================
        float trS[SL];
        #pragma unroll
        for (int q = 0; q < SL / 4; ++q) {
            const float4 t4 = ((const float4*)(trans + lane * Kn + wid * SL))[q];
            trS[4*q+0] = t4.x; trS[4*q+1] = t4.y;
            trS[4*q+2] = t4.z; trS[4*q+3] = t4.w;
        }
        if (wid == 0) sb[0][lane] = (lane == START_TAG) ? 0.0f : NEGV;
        float d = 0.0f;
        int h = lane;
        unsigned int bp4 = 0;
        const size_t dwb = (size_t)b * (Tn / 4);

        float fc[GL], fn[GL];
        #pragma unroll
        for (int k = 0; k < GL; ++k) fc[k] = feats[fb + (size_t)k * Kn + lane];
        bar();
        for (int g = 0; g < NG; ++g) {
            if (g + 1 < NG) {
                const size_t base = fb + (size_t)(g + 1) * GL * Kn + lane;
                #pragma unroll
                for (int k = 0; k < GL; ++k) fn[k] = feats[base + (size_t)k * Kn];
            }
            #pragma unroll
            for (int k = 0; k < GL; ++k) {
                const int t = g * GL + k;
                const int p = t & 1;
                // ---- phase A: slice max+argmax (pre-feat, first-max on ties) ----
                const float4* dp = (const float4*)&sb[p][wid * SL];
                float gv[4]; int gi[4];
                #pragma unroll
                for (int q = 0; q < 4; ++q) {
                    const float4 dv = dp[q];
                    const int i0 = wid * SL + 4 * q;
                    const float sx = dv.x + trS[4*q+0];
                    const float sy = dv.y + trS[4*q+1];
                    const float sz = dv.z + trS[4*q+2];
                    const float sw = dv.w + trS[4*q+3];
                    const bool c01 = sy > sx;
                    const float v01 = c01 ? sy : sx; const int i01 = c01 ? i0+1 : i0;
                    const bool c23 = sw > sz;
                    const float v23 = c23 ? sw : sz; const int i23 = c23 ? i0+3 : i0+2;
                    const bool cq = v23 > v01;
                    gv[q] = cq ? v23 : v01; gi[q] = cq ? i23 : i01;
                }
                const bool ca = gv[1] > gv[0];
                const float va = ca ? gv[1] : gv[0]; const int ia = ca ? gi[1] : gi[0];
                const bool cb = gv[3] > gv[2];
                const float vb = cb ? gv[3] : gv[2]; const int ib = cb ? gi[3] : gi[2];
                const bool cm = vb > va;
                const float m = cm ? vb : va; const int li = cm ? ib : ia;
                // pack: value (monotone) in hi32, (63-idx) in lo32 -> u64 max
                // reproduces global first-max tie semantics exactly.
                kp[p][wid * KP + lane] =
                    ((unsigned long long)fkey(m) << 32) | (unsigned long long)(63 - li);
                bar();
                // ---- phase B: combine 4 partial keys ----
                const unsigned long long k0 = kp[p][0 * KP + lane];
                const unsigned long long k1 = kp[p][1 * KP + lane];
                const unsigned long long k2 = kp[p][2 * KP + lane];
                const unsigned long long k3 = kp[p][3 * KP + lane];
                const unsigned long long ka = k0 > k1 ? k0 : k1;
                const unsigned long long kb = k2 > k3 ? k2 : k3;
                const unsigned long long km = ka > kb ? ka : kb;
                const int bp = 63 - (int)(unsigned int)(km & 0xffffffffULL);
                d = unkey((unsigned int)(km >> 32)) + fc[k];  // feat after argmax
                if (wid == 0) sb[p ^ 1][lane] = d;
                if (wid == 3) {
                    if ((k & 3) == 0) bp4 = (unsigned int)bp;
                    else bp4 |= (unsigned int)bp << (8 * (k & 3));
                    if ((k & 3) == 3)
                        bp32[(dwb + (size_t)(2 * g + (k >> 2))) * Kn + lane] = bp4;
                    h = __shfl(h, bp);
                    if ((t & (CH - 1)) == (CH - 1)) {
                        snap[(t >> 6) * Kn + lane] = (unsigned char)h;
                        h = lane;
                    }
                }
                bar();
            }
            #pragma unroll
            for (int k = 0; k < GL; ++k) fc[k] = fn[k];
        }
        vmdrain();   // bp_ws stores must be visible to wave 0's backtrace reads
        // ---- terminal argmax (first index on ties), wave 3 ----
        if (wid == 3) {
            const float term = d + trans[STOP_TAG * Kn + lane];
            float bv = term;
            int bi = lane;
            #pragma unroll
            for (int off = 32; off; off >>= 1) {
                const float ov = __shfl_xor(bv, off);
                const int oi = __shfl_xor(bi, off);
                if (ov > bv || (ov == bv && oi < bi)) { bv = ov; bi = oi; }
            }
            if (lane == 0) {
                out[BATCH + b] = bv;
                int e = bi;
                for (int c = NCH - 1; c >= 0; --c) {
                    echain[c] = (unsigned char)e;
                    e = snap[c * Kn + e];
                }
            }
        }
        bar();
        // ---- within-chunk reconstruction: wave 0, lane = chunk ----
        if (wid == 0) {
            int tag = echain[lane];
            float* po = out + 2 * BATCH + (size_t)b * Tn;
            for (int k = CH - 1; k >= 0; --k) {
                const int t = lane * CH + k;
                po[t] = (float)tag;
                tag = (int)((bp32[(dwb + (size_t)(t >> 2)) * Kn + tag] >> (8 * (t & 3))) & 63u);
            }
        }
    }
}
} // namespace

extern "C" void kernel_launch(void* const* d_in, const int* in_sizes, int n_in,
                              void* d_out, int out_size, void* d_ws, size_t ws_size,
                              hipStream_t stream)
{
    const float* feats = (const float*)d_in[0];
    const int* tags   = (const int*)d_in[1];
    const float* trans = (const float*)d_in[2];
    float* out = (float*)d_out;
    unsigned int* bp = (unsigned int*)d_ws;  // needs 128*4096*64 B = 32 MB
    hipLaunchKernelGGL(crf_kernel, dim3(2 * BATCH), dim3(256), 0, stream,
                       feats, tags, trans, out, bp);
}

// Round 8
// 1652.870 us; speedup vs baseline: 2.2161x; 1.0528x over previous
//
#include <hip/hip_runtime.h>

namespace {
constexpr int Tn = 4096;
constexpr int Kn = 64;
constexpr int BATCH = 128;
constexpr int START_TAG = 62;
constexpr int STOP_TAG = 63;
constexpr float NEGV = -10000.0f;
constexpr int CH = 64;          // backtrace chunk length
constexpr int NCH = Tn / CH;    // 64 chunks
constexpr int GL = 8;           // feats burst length
constexpr int NG = Tn / GL;     // 512 groups
constexpr int WV = 4;           // waves per block
constexpr int SL = Kn / WV;     // 16 prev-states per wave
constexpr int KP = 66;          // padded partial stride

__device__ __forceinline__ float rfl(float x) {
    return __uint_as_float(__builtin_amdgcn_readfirstlane(__float_as_uint(x)));
}
// LDS-only barrier: waits lgkmcnt but NOT vmcnt, so global bursts stay in flight.
__device__ __forceinline__ void bar() {
    __asm__ volatile("s_waitcnt lgkmcnt(0)\n\ts_barrier" ::: "memory");
}
__device__ __forceinline__ void vmdrain() {
    __asm__ volatile("s_waitcnt vmcnt(0)" ::: "memory");
}
// monotone float->u32 map (preserves fp32 ordering exactly)
__device__ __forceinline__ unsigned int fkey(float x) {
    unsigned int b = __float_as_uint(x);
    return (b & 0x80000000u) ? ~b : (b | 0x80000000u);
}
__device__ __forceinline__ float unkey(unsigned int hb) {
    return __uint_as_float((hb & 0x80000000u) ? (hb ^ 0x80000000u) : ~hb);
}

__global__ __launch_bounds__(256)
void crf_kernel(const float* __restrict__ feats,   // [B,T,K]
                const int* __restrict__ tags,      // [B,T]
                const float* __restrict__ trans,   // [K,K]  trans[next,prev]
                float* __restrict__ out,           // [B] nll | [B] path_score | [B,T] path
                unsigned int* __restrict__ bp32)   // [B,T/4,K] packed backpointers
{
    const int tid = threadIdx.x;
    const int lane = tid & 63;
    const int wid = tid >> 6;
    const int b = blockIdx.x & (BATCH - 1);
    const size_t fb = (size_t)b * Tn * Kn;

    __shared__ float pvs[WV][2][Kn];              // fwd: per-wave private v copies
    __shared__ float wp[2][WV * KP];              // fwd partial sums
    __shared__ float dvs[WV][2][Kn];              // vit: per-wave private delta copies
    __shared__ unsigned long long kp[2][WV * KP]; // vit partial keys
    __shared__ float gw[WV];                      // gold partial per wave
    __shared__ unsigned char snap[NCH * Kn];
    __shared__ unsigned char echain[NCH];

    if (blockIdx.x < BATCH) {
        // ================= forward log-partition + gold -> nll =================
        // ---- gold: 256 threads x 16 steps each ----
        float gold = 0.0f;
        {
            const int t0 = tid * (Tn / 256);
            int prev = (tid == 0) ? START_TAG : tags[(size_t)b * Tn + t0 - 1];
            for (int k = 0; k < Tn / 256; ++k) {
                const int t = t0 + k;
                const int tg = tags[(size_t)b * Tn + t];
                gold += trans[tg * Kn + prev] + feats[fb + (size_t)t * Kn + tg];
                prev = tg;
            }
            if (tid == 255) gold += trans[STOP_TAG * Kn + prev];
            #pragma unroll
            for (int off = 32; off; off >>= 1) gold += __shfl_down(gold, off);
            if (lane == 0) gw[wid] = gold;  // visible by the loop's barriers
        }
        // slice of exp(trans): ES[s] = exp(trans[lane, wid*16+s])
        float ES[SL];
        #pragma unroll
        for (int q = 0; q < SL / 4; ++q) {
            const float4 t4 = ((const float4*)(trans + lane * Kn + wid * SL))[q];
            ES[4*q+0] = __expf(t4.x); ES[4*q+1] = __expf(t4.y);
            ES[4*q+2] = __expf(t4.z); ES[4*q+3] = __expf(t4.w);
        }
        // exp-domain one-hot init (generic step at t=0 reproduces ref exactly)
        pvs[wid][0][lane] = (lane == START_TAG) ? 1.0f : 0.0f;
        float O = 0.0f, v = 0.0f;

        float fc[GL], fn[GL], Fc[GL];
        #pragma unroll
        for (int k = 0; k < GL; ++k) fc[k] = feats[fb + (size_t)k * Kn + lane];
        bar();
        for (int g = 0; g < NG; ++g) {
            if (g + 1 < NG) {
                const size_t base = fb + (size_t)(g + 1) * GL * Kn + lane;
                #pragma unroll
                for (int k = 0; k < GL; ++k) fn[k] = feats[base + (size_t)k * Kn];
            }
            #pragma unroll
            for (int k = 0; k < GL; ++k) Fc[k] = __expf(fc[k]);
            #pragma unroll
            for (int k = 0; k < GL; ++k) {
                const int t = g * GL + k;
                const int p = t & 1;
                // ---- phase A: partial dot over this wave's 16 prev states,
                //      read from OWN private copy (broadcast reads, no barrier) ----
                const float4* vp = (const float4*)&pvs[wid][p][wid * SL];
                const float4 v0 = vp[0], v1 = vp[1], v2 = vp[2], v3 = vp[3];
                float s0 = 0.f, s1 = 0.f, s2 = 0.f, s3 = 0.f;
                s0 = fmaf(ES[0],  v0.x, s0); s1 = fmaf(ES[1],  v0.y, s1);
                s2 = fmaf(ES[2],  v0.z, s2); s3 = fmaf(ES[3],  v0.w, s3);
                s0 = fmaf(ES[4],  v1.x, s0); s1 = fmaf(ES[5],  v1.y, s1);
                s2 = fmaf(ES[6],  v1.z, s2); s3 = fmaf(ES[7],  v1.w, s3);
                s0 = fmaf(ES[8],  v2.x, s0); s1 = fmaf(ES[9],  v2.y, s1);
                s2 = fmaf(ES[10], v2.z, s2); s3 = fmaf(ES[11], v2.w, s3);
                s0 = fmaf(ES[12], v3.x, s0); s1 = fmaf(ES[13], v3.y, s1);
                s2 = fmaf(ES[14], v3.z, s2); s3 = fmaf(ES[15], v3.w, s3);
                wp[p][wid * KP + lane] = (s0 + s1) + (s2 + s3);
                bar();                           // the ONLY barrier per step
                // ---- phase B: combine 4 partials (fixed order), renormalize,
                //      write own private copy (same-wave: no barrier needed) ----
                const float w0r = wp[p][0 * KP + lane];
                const float w1r = wp[p][1 * KP + lane];
                const float w2r = wp[p][2 * KP + lane];
                const float w3r = wp[p][3 * KP + lane];
                const float w = ((w0r + w1r) + (w2r + w3r)) * Fc[k];
                const float wz = rfl(w);         // lane-0 value > 0
                O += __logf(wz);                 // off-chain log accumulation
                v = w * __builtin_amdgcn_rcpf(wz);
                pvs[wid][p ^ 1][lane] = v;
            }
            #pragma unroll
            for (int k = 0; k < GL; ++k) fc[k] = fn[k];
        }
        // ---- nll = logsumexp(alpha + trans[STOP,:]) - gold (wave 0 writes) ----
        if (wid == 0) {
            const float a = O + __logf(v);       // v==0 -> -inf, fine
            const float x = a + trans[STOP_TAG * Kn + lane];
            float mx = x;
            #pragma unroll
            for (int off = 32; off; off >>= 1) mx = fmaxf(mx, __shfl_xor(mx, off));
            float se = __expf(x - mx);
            #pragma unroll
            for (int off = 32; off; off >>= 1) se += __shfl_xor(se, off);
            if (lane == 0)
                out[b] = (mx + __logf(se)) - (((gw[0] + gw[1]) + (gw[2] + gw[3])));
        }
    } else {
        // ================= Viterbi decode (exact fp32) =================
        float trS[SL];
        #pragma unroll
        for (int q = 0; q < SL / 4; ++q) {
            const float4 t4 = ((const float4*)(trans + lane * Kn + wid * SL))[q];
            trS[4*q+0] = t4.x; trS[4*q+1] = t4.y;
            trS[4*q+2] = t4.z; trS[4*q+3] = t4.w;
        }
        dvs[wid][0][lane] = (lane == START_TAG) ? 0.0f : NEGV;
        float d = 0.0f;
        int h = lane;
        unsigned int bp4 = 0;
        const size_t dwb = (size_t)b * (Tn / 4);

        float fc[GL], fn[GL];
        #pragma unroll
        for (int k = 0; k < GL; ++k) fc[k] = feats[fb + (size_t)k * Kn + lane];
        bar();
        for (int g = 0; g < NG; ++g) {
            if (g + 1 < NG) {
                const size_t base = fb + (size_t)(g + 1) * GL * Kn + lane;
                #pragma unroll
                for (int k = 0; k < GL; ++k) fn[k] = feats[base + (size_t)k * Kn];
            }
            #pragma unroll
            for (int k = 0; k < GL; ++k) {
                const int t = g * GL + k;
                const int p = t & 1;
                // ---- phase A: slice max+argmax from OWN private copy ----
                const float4* dp = (const float4*)&dvs[wid][p][wid * SL];
                float gv[4]; int gi[4];
                #pragma unroll
                for (int q = 0; q < 4; ++q) {
                    const float4 dv = dp[q];
                    const int i0 = wid * SL + 4 * q;
                    const float sx = dv.x + trS[4*q+0];
                    const float sy = dv.y + trS[4*q+1];
                    const float sz = dv.z + trS[4*q+2];
                    const float sw = dv.w + trS[4*q+3];
                    const bool c01 = sy > sx;
                    const float v01 = c01 ? sy : sx; const int i01 = c01 ? i0+1 : i0;
                    const bool c23 = sw > sz;
                    const float v23 = c23 ? sw : sz; const int i23 = c23 ? i0+3 : i0+2;
                    const bool cq = v23 > v01;
                    gv[q] = cq ? v23 : v01; gi[q] = cq ? i23 : i01;
                }
                const bool ca = gv[1] > gv[0];
                const float va = ca ? gv[1] : gv[0]; const int ia = ca ? gi[1] : gi[0];
                const bool cb = gv[3] > gv[2];
                const float vb = cb ? gv[3] : gv[2]; const int ib = cb ? gi[3] : gi[2];
                const bool cm = vb > va;
                const float m = cm ? vb : va; const int li = cm ? ib : ia;
                // pack: value (monotone) hi32, (63-idx) lo32 -> u64 max == first-max
                kp[p][wid * KP + lane] =
                    ((unsigned long long)fkey(m) << 32) | (unsigned long long)(63 - li);
                bar();                           // the ONLY barrier per step
                // ---- phase B: combine 4 partial keys, write own private copy ----
                const unsigned long long k0 = kp[p][0 * KP + lane];
                const unsigned long long k1 = kp[p][1 * KP + lane];
                const unsigned long long k2 = kp[p][2 * KP + lane];
                const unsigned long long k3 = kp[p][3 * KP + lane];
                const unsigned long long ka = k0 > k1 ? k0 : k1;
                const unsigned long long kb = k2 > k3 ? k2 : k3;
                const unsigned long long km = ka > kb ? ka : kb;
                const int bp = 63 - (int)(unsigned int)(km & 0xffffffffULL);
                d = unkey((unsigned int)(km >> 32)) + fc[k];  // feat after argmax
                dvs[wid][p ^ 1][lane] = d;
                if (wid == 3) {
                    if ((k & 3) == 0) bp4 = (unsigned int)bp;
                    else bp4 |= (unsigned int)bp << (8 * (k & 3));
                    if ((k & 3) == 3)
                        bp32[(dwb + (size_t)(2 * g + (k >> 2))) * Kn + lane] = bp4;
                    h = __shfl(h, bp);
                    if ((t & (CH - 1)) == (CH - 1)) {
                        snap[(t >> 6) * Kn + lane] = (unsigned char)h;
                        h = lane;
                    }
                }
            }
            #pragma unroll
            for (int k = 0; k < GL; ++k) fc[k] = fn[k];
        }
        vmdrain();   // bp32 stores (wave 3) land before backtrace reads
        // ---- terminal argmax (first index on ties), wave 3 ----
        if (wid == 3) {
            const float term = d + trans[STOP_TAG * Kn + lane];
            float bv = term;
            int bi = lane;
            #pragma unroll
            for (int off = 32; off; off >>= 1) {
                const float ov = __shfl_xor(bv, off);
                const int oi = __shfl_xor(bi, off);
                if (ov > bv || (ov == bv && oi < bi)) { bv = ov; bi = oi; }
            }
            if (lane == 0) {
                out[BATCH + b] = bv;
                int e = bi;
                for (int c = NCH - 1; c >= 0; --c) {
                    echain[c] = (unsigned char)e;
                    e = snap[c * Kn + e];
                }
            }
        }
        bar();
        // ---- within-chunk reconstruction: wave 0, lane = chunk ----
        if (wid == 0) {
            int tag = echain[lane];
            float* po = out + 2 * BATCH + (size_t)b * Tn;
            for (int k = CH - 1; k >= 0; --k) {
                const int t = lane * CH + k;
                po[t] = (float)tag;
                tag = (int)((bp32[(dwb + (size_t)(t >> 2)) * Kn + tag] >> (8 * (t & 3))) & 63u);
            }
        }
    }
}
} // namespace

extern "C" void kernel_launch(void* const* d_in, const int* in_sizes, int n_in,
                              void* d_out, int out_size, void* d_ws, size_t ws_size,
                              hipStream_t stream)
{
    const float* feats = (const float*)d_in[0];
    const int* tags   = (const int*)d_in[1];
    const float* trans = (const float*)d_in[2];
    float* out = (float*)d_out;
    unsigned int* bp = (unsigned int*)d_ws;  // needs 128*4096*64 B = 32 MB
    hipLaunchKernelGGL(crf_kernel, dim3(2 * BATCH), dim3(256), 0, stream,
                       feats, tags, trans, out, bp);
}